// Round 4
// baseline (335.883 us; speedup 1.0000x reference)
//
#include <hip/hip_runtime.h>

#define LOG2E 1.4426950408889634f
#define LN2   0.6931471805599453f
#define PSC   8.0f

typedef __attribute__((ext_vector_type(8))) short bf16x8;
typedef __attribute__((ext_vector_type(4))) float f32x4;

__device__ __forceinline__ uint2 pk2(f32x4 v){
  unsigned x0=__float_as_uint(v.x), x1=__float_as_uint(v.y),
           x2=__float_as_uint(v.z), x3=__float_as_uint(v.w);
  uint2 r; r.x = (x1 & 0xFFFF0000u) | (x0>>16);
           r.y = (x3 & 0xFFFF0000u) | (x2>>16);
  return r;
}

// 16 blocks x 512 threads. Block handles 16 batches.
// wave 0: MFMA scan consumer. waves 1..7: E-producer pipeline (16-step deep).
// p stored [b][tag] bf16 in LDS ping-pong (XOR-swizzled); W^T in bf16 A-frags (regs).
__global__ void __launch_bounds__(512)
patcrf_fwd(const float* __restrict__ le, const float* __restrict__ pe,
           const int* __restrict__ y, const float* __restrict__ lt,
           const int* __restrict__ t2l, const float* __restrict__ tp,
           const float* __restrict__ tc, const unsigned int* __restrict__ smask,
           float* __restrict__ out)
{
  __shared__ __align__(16) float E_f[16*16*64];          // [slot][b][tag]
  __shared__ __align__(16) float trans_lds[4096];        // nat-log transitions [i][j]
  __shared__ __align__(16) unsigned short pbuf[2][1024]; // [par][b][tag] bf16
  __shared__ __align__(16) float tp_lds[256];
  __shared__ __align__(16) float startf[64];
  __shared__ float scpart[16];
  __shared__ int t2l_lds[64];

  const int tid  = threadIdx.x;
  const int wv   = tid >> 6;
  const int lane = tid & 63;
  const int bg0  = blockIdx.x * 16;

  // ---- stage small tables ----
  if (tid < 64){
    bool all01=true, allf=true;
    #pragma unroll
    for (int k=0;k<16;k++){ unsigned v = smask[k]; all01 = all01 && (v<=1u); allf = allf && (v==0u||v==0x3F800000u); }
    int sv;
    if (all01)      sv = ((const int*)smask)[tid];
    else if (allf)  sv = (((const unsigned*)smask)[tid] != 0u) ? 1 : 0;
    else            sv = ((const unsigned char*)smask)[tid];
    startf[tid] = sv ? 1.0f : 0.0f;
    t2l_lds[tid] = t2l[tid];
    *(f32x4*)(tp_lds + tid*4) = *(const f32x4*)(tp + tid*4);
  }
  __syncthreads();
  #pragma unroll
  for (int k=0;k<8;k++){
    int idx = k*512 + tid;
    trans_lds[idx] = lt[t2l_lds[idx>>6]*32 + t2l_lds[idx&63]] + tc[idx];
  }
  __syncthreads();

  // ---- score phase: thread (b = tid>>5) covers s in [(tid&31)*32, +32) ----
  {
    int b_ = tid>>5, s0_ = (tid&31)*32;
    const int*   yb  = y  + (size_t)(bg0+b_)*1024;
    const float* leB = le + (size_t)(bg0+b_)*1024*32;
    const float* peB = pe + (size_t)(bg0+b_)*1024*4;
    float scl = 0.f;
    int yc = yb[s0_];
    #pragma unroll 4
    for (int k=0;k<32;k++){
      int s = s0_+k;
      int yn = (s<1023) ? yb[s+1] : 0;
      f32x4 p4 = *(const f32x4*)(peB + (size_t)s*4);
      f32x4 t4 = *(const f32x4*)(tp_lds + yc*4);
      float xv = leB[(size_t)s*32 + t2l_lds[yc]]
               + p4.x*t4.x + p4.y*t4.y + p4.z*t4.z + p4.w*t4.w;
      scl += xv;
      if (s<1023) scl += trans_lds[yc*64 + yn];
      yc = yn;
    }
    scl += __shfl_xor(scl,1);  scl += __shfl_xor(scl,2);
    scl += __shfl_xor(scl,4);  scl += __shfl_xor(scl,8);
    scl += __shfl_xor(scl,16);
    if ((lane&31)==0) scpart[b_] = scl;
  }

  // ---- producer state / macros ----
  int myl = 0; f32x4 mytp = {0,0,0,0};
  float leR[12]; f32x4 peR[12];
  const int pb0 = wv-1, pb1 = wv+6, pb2 = wv+13;

#define PROD_LOAD(TB) do{ \
    _Pragma("unroll") \
    for (int k_=0;k_<12;k_++){ \
      int pb_ = (k_<4)?pb0:((k_<8)?pb1:pb2); \
      int s_  = (TB) + (k_&3); \
      if (pb_ < 16){ \
        size_t base_ = ((size_t)(bg0+pb_)*1024 + s_); \
        leR[k_] = le[base_*32 + myl]; \
        peR[k_] = *(const f32x4*)(pe + base_*4); \
      } \
    } \
  }while(0)

#define PROD_COMP(TB) do{ \
    _Pragma("unroll") \
    for (int k_=0;k_<12;k_++){ \
      int pb_ = (k_<4)?pb0:((k_<8)?pb1:pb2); \
      int s_  = (TB) + (k_&3); \
      if (pb_ < 16){ \
        f32x4 q_ = peR[k_]; \
        float x2_ = (leR[k_] + (q_.x*mytp.x + q_.y*mytp.y + q_.z*mytp.z + q_.w*mytp.w))*LOG2E - PSC; \
        E_f[(s_&15)*1024 + pb_*64 + lane] = __builtin_amdgcn_exp2f(x2_); \
      } \
    } \
  }while(0)

  // ---- consumer state ----
  const int bb = lane & 15, jj = lane >> 4;
  const int swz = (bb & 7) << 4;
  const int rdoff0 = (bb*128 + jj*16)      ^ swz;
  const int rdoff1 = (bb*128 + jj*16 + 64) ^ swz;
  const int wr0 = (bb*128 + 0*32 + jj*8) ^ swz;
  const int wr1 = (bb*128 + 1*32 + jj*8) ^ swz;
  const int wr2 = (bb*128 + 2*32 + jj*8) ^ swz;
  const int wr3 = (bb*128 + 3*32 + jj*8) ^ swz;
  const int ebo = bb*64 + jj*4;
  const f32x4 zf = {0.f,0.f,0.f,0.f};
  bf16x8 Wf00,Wf01,Wf10,Wf11,Wf20,Wf21,Wf30,Wf31;
  f32x4 v0,v1,v2,v3;
  float scv = 1.0f, L2 = 0.0f;

  if (wv == 0){
    // A-frags: A[row=16m+bb][k=32h+8jj+c] = W[k][row] = exp(trans[k][row])
    auto mk = [&](int m, int h){
      bf16x8 r;
      #pragma unroll
      for (int c=0;c<8;c++){
        float w_ = __builtin_amdgcn_exp2f(trans_lds[(32*h + 8*jj + c)*64 + 16*m + bb]*LOG2E);
        unsigned u_ = __float_as_uint(w_);
        unsigned b_ = (u_ + 0x7FFFu + ((u_>>16)&1u)) >> 16;
        r[c] = (short)b_;
      }
      return r;
    };
    Wf00=mk(0,0); Wf01=mk(0,1); Wf10=mk(1,0); Wf11=mk(1,1);
    Wf20=mk(2,0); Wf21=mk(2,1); Wf30=mk(3,0); Wf31=mk(3,1);
  } else {
    myl  = t2l_lds[lane];
    mytp = *(const f32x4*)(tp_lds + lane*4);
    // prologue: fill E for steps 0..11, issue loads for 12..15
    PROD_LOAD(0);  PROD_COMP(0);
    PROD_LOAD(4);  PROD_COMP(4);
    PROD_LOAD(8);  PROD_COMP(8);
    PROD_LOAD(12);
  }
  __syncthreads();   // E[0..11] visible

  // one scan step: read p^(T-1) from pbuf[WPAR^1], write p^T to pbuf[WPAR]
#define CSTEP(WPAR, SLOT, APPLY) do { \
    const char* rb_ = (const char*)pbuf[(WPAR)^1]; \
    char* wb_ = (char*)pbuf[(WPAR)]; \
    bf16x8 B0_ = *(const bf16x8*)(rb_ + rdoff0); \
    bf16x8 B1_ = *(const bf16x8*)(rb_ + rdoff1); \
    const float* ep_ = E_f + (SLOT)*1024 + ebo; \
    f32x4 e0_ = *(const f32x4*)(ep_);    f32x4 e1_ = *(const f32x4*)(ep_+16); \
    f32x4 e2_ = *(const f32x4*)(ep_+32); f32x4 e3_ = *(const f32x4*)(ep_+48); \
    if (APPLY){ e0_*=scv; e1_*=scv; e2_*=scv; e3_*=scv; } \
    f32x4 a0_ = __builtin_amdgcn_mfma_f32_16x16x32_bf16(Wf00, B0_, zf, 0,0,0); \
    f32x4 a1_ = __builtin_amdgcn_mfma_f32_16x16x32_bf16(Wf10, B0_, zf, 0,0,0); \
    f32x4 a2_ = __builtin_amdgcn_mfma_f32_16x16x32_bf16(Wf20, B0_, zf, 0,0,0); \
    f32x4 a3_ = __builtin_amdgcn_mfma_f32_16x16x32_bf16(Wf30, B0_, zf, 0,0,0); \
    a0_ = __builtin_amdgcn_mfma_f32_16x16x32_bf16(Wf01, B1_, a0_, 0,0,0); \
    a1_ = __builtin_amdgcn_mfma_f32_16x16x32_bf16(Wf11, B1_, a1_, 0,0,0); \
    a2_ = __builtin_amdgcn_mfma_f32_16x16x32_bf16(Wf21, B1_, a2_, 0,0,0); \
    a3_ = __builtin_amdgcn_mfma_f32_16x16x32_bf16(Wf31, B1_, a3_, 0,0,0); \
    v0 = a0_*e0_; v1 = a1_*e1_; v2 = a2_*e2_; v3 = a3_*e3_; \
    *(uint2*)(wb_ + wr0) = pk2(v0); \
    *(uint2*)(wb_ + wr1) = pk2(v1); \
    *(uint2*)(wb_ + wr2) = pk2(v2); \
    *(uint2*)(wb_ + wr3) = pk2(v3); \
  } while(0)

  if (wv == 0){
    // p0 from E[0] * start mask -> pbuf[0]
    const float* ep_ = E_f + ebo;
    f32x4 e0_ = *(const f32x4*)(ep_);    f32x4 e1_ = *(const f32x4*)(ep_+16);
    f32x4 e2_ = *(const f32x4*)(ep_+32); f32x4 e3_ = *(const f32x4*)(ep_+48);
    f32x4 m0_ = *(const f32x4*)(startf + 4*jj);
    f32x4 m1_ = *(const f32x4*)(startf + 4*jj + 16);
    f32x4 m2_ = *(const f32x4*)(startf + 4*jj + 32);
    f32x4 m3_ = *(const f32x4*)(startf + 4*jj + 48);
    v0 = e0_*m0_; v1 = e1_*m1_; v2 = e2_*m2_; v3 = e3_*m3_;
    char* wb_ = (char*)pbuf[0];
    *(uint2*)(wb_ + wr0) = pk2(v0);
    *(uint2*)(wb_ + wr1) = pk2(v1);
    *(uint2*)(wb_ + wr2) = pk2(v2);
    *(uint2*)(wb_ + wr3) = pk2(v3);
  }

  // ---- main loop: epochs of 4 steps, t = 1..1020 ----
  #pragma unroll 1
  for (int g=0; g<255; ++g){
    if (wv == 0){
      int t0 = 1 + 4*g;
      CSTEP(1, (t0  )&15, 0);
      CSTEP(0, (t0+1)&15, 1);    // apply previous epoch's renorm scale
      CSTEP(1, (t0+2)&15, 0);
      CSTEP(0, (t0+3)&15, 0);
      // measure renorm (applied next epoch at k1)
      float s16 = (((v0.x+v0.y)+(v0.z+v0.w)) + ((v1.x+v1.y)+(v1.z+v1.w)))
                + (((v2.x+v2.y)+(v2.z+v2.w)) + ((v3.x+v3.y)+(v3.z+v3.w)));
      float S_ = s16 + __shfl_xor(s16, 16);
      S_ += __shfl_xor(S_, 32);
      L2 += __builtin_amdgcn_logf(S_);         // v_log_f32 = log2
      scv = __builtin_amdgcn_rcpf(S_);
    } else {
      int tb = 12 + 4*g;
      if (tb <= 1020) PROD_COMP(tb);
      int tn = tb + 4;
      if (tn <= 1020) PROD_LOAD(tn);
    }
    __syncthreads();
  }

  if (wv == 0){
    // tail: t = 1021, 1022, 1023 (slots 13,14,15)
    CSTEP(1, 13, 0);
    CSTEP(0, 14, 1);
    CSTEP(1, 15, 0);
    // finalize
    float s16 = (((v0.x+v0.y)+(v0.z+v0.w)) + ((v1.x+v1.y)+(v1.z+v1.w)))
              + (((v2.x+v2.y)+(v2.z+v2.w)) + ((v3.x+v3.y)+(v3.z+v3.w)));
    float Sf = s16 + __shfl_xor(s16, 16);
    Sf += __shfl_xor(Sf, 32);
    float logZ = LN2 * (L2 + PSC*1024.0f + __builtin_amdgcn_logf(Sf));
    if (lane < 16) out[bg0 + lane] = scpart[lane] - logZ;
  }
#undef CSTEP
#undef PROD_LOAD
#undef PROD_COMP
}

extern "C" void kernel_launch(void* const* d_in, const int* in_sizes, int n_in,
                              void* d_out, int out_size, void* d_ws, size_t ws_size,
                              hipStream_t stream)
{
  patcrf_fwd<<<16, 512, 0, stream>>>(
    (const float*)d_in[0],          // label_emissions [B,S,32]
    (const float*)d_in[1],          // pattern_emissions [B,S,4]
    (const int*)d_in[2],            // y [B,S]
    (const float*)d_in[3],          // label_transitions [32,32]
    (const int*)d_in[4],            // tag2label [64]
    (const float*)d_in[5],          // tag_patterns [64,4]
    (const float*)d_in[6],          // transition_constraints [64,64]
    (const unsigned int*)d_in[7],   // start_mask [64] (repr sniffed)
    (float*)d_out);
}

// Round 6
// 303.121 us; speedup vs baseline: 1.1081x; 1.1081x over previous
//
#include <hip/hip_runtime.h>

#define LOG2E 1.4426950408889634f
#define LN2   0.6931471805599453f
#define PSC   8.0f

typedef __attribute__((ext_vector_type(4))) float f32x4;

#define CL(s_) ((s_) > 1023 ? 1023 : (s_))

// wave64 all-lane sum via DPP cascade, result broadcast from lane 63
__device__ __forceinline__ float wave_sum64(float v){
#define DADD(ctrl) { int _t = __builtin_amdgcn_update_dpp(0, __float_as_int(v), ctrl, 0xF, 0xF, false); \
                     v = v + __int_as_float(_t); }
  DADD(0x111) DADD(0x112) DADD(0x114) DADD(0x118) DADD(0x142) DADD(0x143)
#undef DADD
  return __int_as_float(__builtin_amdgcn_readlane(__float_as_int(v), 63));
}

// 2 waves per batch. wave 0 = scan chain (lane = tag j), wave 1 = e2 producer.
// p (f32, 64 lanes) exchanged via LDS broadcast reads; e2 pipeline in LDS,
// double-buffered by 8-step group; one __syncthreads per group.
// Scaled product domain: alpha_j(t) = q_j * 2^(L2 + PSC*(t+1)); renorm per group.
__global__ void __launch_bounds__(128, 1)
patcrf_fwd(const float* __restrict__ le, const float* __restrict__ pe,
           const int* __restrict__ y, const float* __restrict__ lt,
           const int* __restrict__ t2l, const float* __restrict__ tp,
           const float* __restrict__ tc, const unsigned int* __restrict__ smask,
           float* __restrict__ out)
{
  const int b    = blockIdx.x;
  const int tid  = threadIdx.x;
  const int wv   = tid >> 6;
  const int lane = tid & 63;

  __shared__ __align__(16) float E[2][8][64];     // e2 values (pre-scaled 2^-PSC)
  __shared__ __align__(16) float pf[64];          // p exchange
  __shared__ float trans_lds[64*64];              // natural-log transitions [i][j]
  __shared__ __align__(16) float tp_lds[64*4];
  __shared__ int y_lds[1024];
  __shared__ int t2l_lds[64];
  __shared__ float scpart[2];

  // ---- stage 1: small tables ----
  if (tid < 64){
    t2l_lds[tid] = t2l[tid];
    *(f32x4*)(tp_lds + tid*4) = *(const f32x4*)(tp + tid*4);
  }
  const int* yb = y + b*1024;
  *(int4*)(y_lds + tid*8)     = *(const int4*)(yb + tid*8);
  *(int4*)(y_lds + tid*8 + 4) = *(const int4*)(yb + tid*8 + 4);
  __syncthreads();

  // ---- stage 2: transitions ----
  #pragma unroll
  for (int k=0;k<32;k++){
    int idx = k*128 + tid;
    trans_lds[idx] = lt[t2l_lds[idx>>6]*32 + t2l_lds[idx&63]] + tc[idx];
  }
  __syncthreads();

  const int   myl   = t2l_lds[lane];
  const f32x4 mytp4 = *(const f32x4*)(tp_lds + lane*4);
  const float* leb = le + (size_t)b*1024*32;
  const float* peb = pe + (size_t)b*1024*4;

  // ---- score phase: both waves, 8 consecutive s per thread ----
  {
    int s0 = tid*8;
    int yc = y_lds[s0];
    float scl = 0.f;
    #pragma unroll
    for (int k=0;k<8;k++){
      int s = s0+k;
      int yn = (s<1023) ? y_lds[s+1] : 0;
      f32x4 p4 = *(const f32x4*)(peb + (size_t)s*4);
      f32x4 t4 = *(const f32x4*)(tp_lds + yc*4);
      scl += leb[(size_t)s*32 + t2l_lds[yc]]
           + p4.x*t4.x + p4.y*t4.y + p4.z*t4.z + p4.w*t4.w;
      if (s<1023) scl += trans_lds[yc*64 + yn];
      yc = yn;
    }
    float scw = wave_sum64(scl);
    if (lane==0) scpart[wv] = scw;
  }

  // ---- per-wave prologue ----
  float wreg[64];                 // consumer: W column j
  float q = 0.f, L2 = 0.f;
  float leA[8]; f32x4 peA[8];     // producer: raw emissions pipeline

  if (wv == 0){
    #pragma unroll
    for (int i=0;i<64;i++)
      wreg[i] = __builtin_amdgcn_exp2f(trans_lds[i*64 + lane]*LOG2E);

    // start-mask sniff (bool bytes vs int32 vs float32)
    bool all01 = true, allf = true;
    #pragma unroll
    for (int k=0;k<16;k++){
      unsigned v = smask[k];
      all01 = all01 && (v <= 1u);
      allf  = allf  && (v == 0u || v == 0x3F800000u);
    }
    int startv;
    if (all01)      startv = ((const int*)smask)[lane];
    else if (allf)  startv = (((const unsigned*)smask)[lane] != 0u) ? 1 : 0;
    else            startv = ((const unsigned char*)smask)[lane];

    f32x4 pe0 = *(const f32x4*)peb;
    float x0 = leb[myl] + pe0.x*mytp4.x + pe0.y*mytp4.y + pe0.z*mytp4.z + pe0.w*mytp4.w;
    q = startv ? __builtin_amdgcn_exp2f(x0*LOG2E - PSC) : 0.0f;
  } else {
    // E group 0 (steps 1..8) direct
    #pragma unroll
    for (int k=0;k<8;k++){
      int s = 1+k;
      float lv = leb[(size_t)s*32 + myl];
      f32x4 pv = *(const f32x4*)(peb + (size_t)s*4);
      E[0][k][lane] = __builtin_amdgcn_exp2f(
        (lv + pv.x*mytp4.x + pv.y*mytp4.y + pv.z*mytp4.z + pv.w*mytp4.w)*LOG2E - PSC);
    }
    // raw group 1 (steps 9..16)
    #pragma unroll
    for (int k=0;k<8;k++){
      int s = 9+k;
      leA[k] = leb[(size_t)s*32 + myl];
      peA[k] = *(const f32x4*)(peb + (size_t)s*4);
    }
  }
  __syncthreads();   // E[0] visible

  const f32x4* pfv = (const f32x4*)pf;

#define CSTEP(EV) do{ \
    pf[lane] = q; \
    __builtin_amdgcn_wave_barrier(); \
    asm volatile("" ::: "memory"); \
    float c0_=0.f,c1_=0.f,c2_=0.f,c3_=0.f; \
    _Pragma("unroll") \
    for (int m_=0;m_<16;m_++){ \
      f32x4 r_ = pfv[m_]; \
      c0_ = fmaf(r_.x, wreg[4*m_+0], c0_); \
      c1_ = fmaf(r_.y, wreg[4*m_+1], c1_); \
      c2_ = fmaf(r_.z, wreg[4*m_+2], c2_); \
      c3_ = fmaf(r_.w, wreg[4*m_+3], c3_); \
    } \
    __builtin_amdgcn_wave_barrier(); \
    asm volatile("" ::: "memory"); \
    q = ((c0_+c1_)+(c2_+c3_))*(EV); \
  }while(0)

  // ---- main loop: 127 groups of 8 steps (t = 1..1016) ----
  for (int g=0; g<127; ++g){
    if (wv == 0){
      const float* eh = &E[g&1][0][lane];
      float e0=eh[0], e1=eh[64], e2v=eh[128], e3=eh[192],
            e4=eh[256], e5=eh[320], e6=eh[384], e7=eh[448];
      float S = wave_sum64(q);
      L2 += __builtin_amdgcn_logf(S);          // v_log_f32 = log2
      e1 *= __builtin_amdgcn_rcpf(S);
      CSTEP(e0); CSTEP(e1); CSTEP(e2v); CSTEP(e3);
      CSTEP(e4); CSTEP(e5); CSTEP(e6); CSTEP(e7);
    } else {
      float leB[8]; f32x4 peB[8];
      int sL = 8*g + 17;                        // group g+2 raw
      #pragma unroll
      for (int k=0;k<8;k++){
        int s = CL(sL+k);
        leB[k] = leb[(size_t)s*32 + myl];
        peB[k] = *(const f32x4*)(peb + (size_t)s*4);
      }
      float* Eh = &E[(g+1)&1][0][0];            // group g+1 e2
      #pragma unroll
      for (int k=0;k<8;k++){
        Eh[k*64 + lane] = __builtin_amdgcn_exp2f(
          (leA[k] + peA[k].x*mytp4.x + peA[k].y*mytp4.y
                  + peA[k].z*mytp4.z + peA[k].w*mytp4.w)*LOG2E - PSC);
      }
      #pragma unroll
      for (int k=0;k<8;k++){ leA[k]=leB[k]; peA[k]=peB[k]; }
    }
    __syncthreads();
  }

  // ---- tail: steps 1017..1023 (group 127, half 1) + finalize ----
  if (wv == 0){
    const float* eh = &E[1][0][lane];
    float e0=eh[0], e1=eh[64], e2v=eh[128], e3=eh[192],
          e4=eh[256], e5=eh[320], e6=eh[384];
    float S = wave_sum64(q);
    L2 += __builtin_amdgcn_logf(S);
    e1 *= __builtin_amdgcn_rcpf(S);
    CSTEP(e0); CSTEP(e1); CSTEP(e2v); CSTEP(e3);
    CSTEP(e4); CSTEP(e5); CSTEP(e6);

    float Sf = wave_sum64(q);
    float logZ = LN2 * (L2 + PSC*1024.0f + __builtin_amdgcn_logf(Sf));
    if (lane == 0) out[b] = (scpart[0] + scpart[1]) - logZ;
  }
#undef CSTEP
}

extern "C" void kernel_launch(void* const* d_in, const int* in_sizes, int n_in,
                              void* d_out, int out_size, void* d_ws, size_t ws_size,
                              hipStream_t stream)
{
  patcrf_fwd<<<256, 128, 0, stream>>>(
    (const float*)d_in[0],          // label_emissions [B,S,32]
    (const float*)d_in[1],          // pattern_emissions [B,S,4]
    (const int*)d_in[2],            // y [B,S]
    (const float*)d_in[3],          // label_transitions [32,32]
    (const int*)d_in[4],            // tag2label [64]
    (const float*)d_in[5],          // tag_patterns [64,4]
    (const float*)d_in[6],          // transition_constraints [64,64]
    (const unsigned int*)d_in[7],   // start_mask [64] (repr sniffed)
    (float*)d_out);
}

// Round 7
// 119.916 us; speedup vs baseline: 2.8010x; 2.5278x over previous
//
#include <hip/hip_runtime.h>

#define LOG2E 1.4426950408889634f
#define LN2   0.6931471805599453f
#define PSC   8.0f

typedef __attribute__((ext_vector_type(8))) short bf16x8;
typedef __attribute__((ext_vector_type(4))) float f32x4;
typedef __attribute__((ext_vector_type(4))) unsigned u32x4;

__device__ __forceinline__ unsigned pk_bf16(float lo, float hi){
  unsigned r;
  asm("v_cvt_pk_bf16_f32 %0, %1, %2" : "=v"(r) : "v"(lo), "v"(hi));
  return r;
}

__device__ __forceinline__ float wave_sum64(float v){
#define DADD(ctrl) { int _t = __builtin_amdgcn_update_dpp(0, __float_as_int(v), ctrl, 0xF, 0xF, false); \
                     v = v + __int_as_float(_t); }
  DADD(0x111) DADD(0x112) DADD(0x114) DADD(0x118) DADD(0x142) DADD(0x143)
#undef DADD
  return __int_as_float(__builtin_amdgcn_readlane(__float_as_int(v), 63));
}
__device__ __forceinline__ float wave_max64(float v){
#define DMAX(ctrl) { int _t = __builtin_amdgcn_update_dpp(__float_as_int(v), __float_as_int(v), ctrl, 0xF, 0xF, false); \
                     v = fmaxf(v, __int_as_float(_t)); }
  DMAX(0x111) DMAX(0x112) DMAX(0x114) DMAX(0x118) DMAX(0x142) DMAX(0x143)
#undef DMAX
  return __int_as_float(__builtin_amdgcn_readlane(__float_as_int(v), 63));
}
__device__ __forceinline__ f32x4 vmax4(f32x4 a, f32x4 b){
  f32x4 r; r.x=fmaxf(a.x,b.x); r.y=fmaxf(a.y,b.y); r.z=fmaxf(a.z,b.z); r.w=fmaxf(a.w,b.w); return r;
}

// Block = batch b. Waves 0-3: chunk-matrix consumers (chunk=wv, 256 steps each,
// chunk 0 skips t=0). Waves 4-7: e(t) producers into double-buffered LDS.
// State: P_c as 4x4 f32x4 MFMA accumulators; step: pack acc->B (cvt_pk, no
// cross-lane thanks to sigma-permuted A), 32 MFMA, row-scale by e(t).
// Renorm by power-of-2 every 16 steps (exact). Combine: 4 matvecs in wave 0.
__global__ void __launch_bounds__(512, 1)
patcrf_fwd(const float* __restrict__ le, const float* __restrict__ pe,
           const int* __restrict__ y, const float* __restrict__ lt,
           const int* __restrict__ t2l, const float* __restrict__ tp,
           const float* __restrict__ tc, const unsigned int* __restrict__ smask,
           float* __restrict__ out)
{
  const int b = blockIdx.x;
  const int tid = threadIdx.x;
  const int wv = tid >> 6;
  const int lane = tid & 63;
  const int bb = lane & 15, jj = lane >> 4;

  // Aliased LDS: phase1 {E | trans | y} overlaid by phase2 {P}
  __shared__ __align__(16) char smem[69632];
  float* E_lds     = (float*)smem;              // [4][2][16][64] f32 = 32KB
  float* trans_lds = (float*)(smem + 32768);    // [64][64] nat-log = 16KB
  int*   y_lds     = (int*)(smem + 49152);      // [1024] = 4KB
  float* P_lds     = (float*)smem;              // [4][64*68] row-major (phase 2)
  __shared__ __align__(16) float tp_lds[256];
  __shared__ __align__(16) float pf[64];
  __shared__ int   t2l_lds[64];
  __shared__ float scpart[8];
  __shared__ float L2arr[4];

  // ---- stage tables ----
  if (tid < 64){
    t2l_lds[tid] = t2l[tid];
    *(f32x4*)(tp_lds + tid*4) = *(const f32x4*)(tp + tid*4);
  }
  const int* yb = y + b*1024;
  y_lds[tid] = yb[tid];
  y_lds[tid+512] = yb[tid+512];
  __syncthreads();
  #pragma unroll
  for (int k=0;k<8;k++){
    int idx = k*512 + tid;
    trans_lds[idx] = lt[t2l_lds[idx>>6]*32 + t2l_lds[idx&63]] + tc[idx];
  }
  __syncthreads();

  const float* leb = le + (size_t)b*1024*32;
  const float* peb = pe + (size_t)b*1024*4;

  // ---- score phase: 2 positions per thread ----
  {
    int s0 = tid*2;
    int y0 = y_lds[s0], y1 = y_lds[s0+1];
    f32x4 pA = *(const f32x4*)(peb + (size_t)s0*4);
    f32x4 pB = *(const f32x4*)(peb + (size_t)(s0+1)*4);
    f32x4 tA = *(const f32x4*)(tp_lds + y0*4);
    f32x4 tB = *(const f32x4*)(tp_lds + y1*4);
    float s = leb[(size_t)s0*32 + t2l_lds[y0]]
            + pA.x*tA.x + pA.y*tA.y + pA.z*tA.z + pA.w*tA.w
            + leb[(size_t)(s0+1)*32 + t2l_lds[y1]]
            + pB.x*tB.x + pB.y*tB.y + pB.z*tB.z + pB.w*tB.w;
    s += trans_lds[y0*64 + y1];
    if (s0+2 < 1024) s += trans_lds[y1*64 + y_lds[s0+2]];
    float sw = wave_sum64(s);
    if (lane==0) scpart[wv] = sw;
  }

  if (wv < 4){
    // ================= CONSUMER: chunk product =================
    const int c = wv;
    // A-frags: A[i=16m+bb][k=32h+8jj+cc] = W[sigma][i], sigma=32h+16*(cc>>2)+4jj+(cc&3)
    u32x4 Af[4][2];
    #pragma unroll
    for (int m=0;m<4;m++){
      #pragma unroll
      for (int h=0;h<2;h++){
        unsigned uu[4];
        #pragma unroll
        for (int q=0;q<4;q++){
          int c0 = 2*q, c1 = 2*q+1;
          int sg0 = 32*h + ((c0>>2)<<4) + 4*jj + (c0&3);
          int sg1 = 32*h + ((c1>>2)<<4) + 4*jj + (c1&3);
          float w0 = __builtin_amdgcn_exp2f(trans_lds[sg0*64 + 16*m + bb]*LOG2E);
          float w1 = __builtin_amdgcn_exp2f(trans_lds[sg1*64 + 16*m + bb]*LOG2E);
          uu[q] = pk_bf16(w0, w1);
        }
        Af[m][h] = (u32x4){uu[0],uu[1],uu[2],uu[3]};
      }
    }
    // acc = Identity: acc[m][n][r] = (m==n && bb==4jj+r)
    f32x4 acc[4][4];
    #pragma unroll
    for (int m=0;m<4;m++){
      #pragma unroll
      for (int n=0;n<4;n++){
        f32x4 z;
        z.x = (m==n && bb==4*jj+0) ? 1.f : 0.f;
        z.y = (m==n && bb==4*jj+1) ? 1.f : 0.f;
        z.z = (m==n && bb==4*jj+2) ? 1.f : 0.f;
        z.w = (m==n && bb==4*jj+3) ? 1.f : 0.f;
        acc[m][n] = z;
      }
    }
    float L2c = 0.f;
    const f32x4 zf = {0.f,0.f,0.f,0.f};

    __syncthreads();   // E[buf 0] ready

    for (int ep=0; ep<16; ++ep){
      const float* Eb = E_lds + (c*2 + (ep&1))*1024;
      #pragma unroll 2
      for (int s=0;s<16;s++){
        if (c==0 && ep==0 && s==0) continue;   // chunk 0 starts at t=1
        f32x4 ev[4];
        #pragma unroll
        for (int m=0;m<4;m++) ev[m] = *(const f32x4*)(Eb + s*64 + 16*m + 4*jj);
        // B-frags from own acc regs (sigma-matched, no movement)
        u32x4 Bf[2][4];
        #pragma unroll
        for (int n=0;n<4;n++){
          #pragma unroll
          for (int h=0;h<2;h++){
            Bf[h][n] = (u32x4){
              pk_bf16(acc[2*h][n].x,   acc[2*h][n].y),
              pk_bf16(acc[2*h][n].z,   acc[2*h][n].w),
              pk_bf16(acc[2*h+1][n].x, acc[2*h+1][n].y),
              pk_bf16(acc[2*h+1][n].z, acc[2*h+1][n].w) };
          }
        }
        #pragma unroll
        for (int m=0;m<4;m++){
          #pragma unroll
          for (int n=0;n<4;n++){
            f32x4 d = __builtin_amdgcn_mfma_f32_16x16x32_bf16(
                        __builtin_bit_cast(bf16x8, Af[m][0]),
                        __builtin_bit_cast(bf16x8, Bf[0][n]), zf, 0,0,0);
            d = __builtin_amdgcn_mfma_f32_16x16x32_bf16(
                        __builtin_bit_cast(bf16x8, Af[m][1]),
                        __builtin_bit_cast(bf16x8, Bf[1][n]), d, 0,0,0);
            acc[m][n] = d * ev[m];
          }
        }
      }
      // power-of-2 renorm (exact bookkeeping)
      f32x4 m4 = acc[0][0];
      #pragma unroll
      for (int m=0;m<4;m++){
        #pragma unroll
        for (int n=0;n<4;n++) m4 = vmax4(m4, acc[m][n]);
      }
      float mx = fmaxf(fmaxf(m4.x,m4.y), fmaxf(m4.z,m4.w));
      mx = wave_max64(mx);
      if (mx > 0.f){
        int Ex = (int)(__float_as_uint(mx)>>23) - 127;
        if (Ex != 0){
          float scl = __uint_as_float((unsigned)(127 - Ex) << 23);
          #pragma unroll
          for (int m=0;m<4;m++){
            #pragma unroll
            for (int n=0;n<4;n++) acc[m][n] = acc[m][n]*scl;
          }
          L2c += (float)Ex;
        }
      }
      __syncthreads();
    }

    // write P_c row-major stride 68 (aliases E/trans — all dead now)
    float* Pc = P_lds + c*4352;
    #pragma unroll
    for (int m=0;m<4;m++){
      #pragma unroll
      for (int n=0;n<4;n++){
        Pc[(16*m+4*jj+0)*68 + 16*n + bb] = acc[m][n].x;
        Pc[(16*m+4*jj+1)*68 + 16*n + bb] = acc[m][n].y;
        Pc[(16*m+4*jj+2)*68 + 16*n + bb] = acc[m][n].z;
        Pc[(16*m+4*jj+3)*68 + 16*n + bb] = acc[m][n].w;
      }
    }
    if (lane==0) L2arr[c] = L2c;

  } else {
    // ================= PRODUCER: e(t) pipeline =================
    const int c = wv - 4;
    const int myl = t2l_lds[lane];
    const f32x4 myt = *(const f32x4*)(tp_lds + lane*4);
    float leA[16]; f32x4 peA[16];
    // epoch 0 direct
    #pragma unroll
    for (int s=0;s<16;s++){
      int t = 256*c + s;
      leA[s] = leb[(size_t)t*32 + myl];
      peA[s] = *(const f32x4*)(peb + (size_t)t*4);
    }
    #pragma unroll
    for (int s=0;s<16;s++){
      float x2 = (leA[s] + peA[s].x*myt.x + peA[s].y*myt.y
                         + peA[s].z*myt.z + peA[s].w*myt.w)*LOG2E - PSC;
      E_lds[(c*2+0)*1024 + s*64 + lane] = __builtin_amdgcn_exp2f(x2);
    }
    // raw epoch 1
    #pragma unroll
    for (int s=0;s<16;s++){
      int t = 256*c + 16 + s;
      leA[s] = leb[(size_t)t*32 + myl];
      peA[s] = *(const f32x4*)(peb + (size_t)t*4);
    }
    __syncthreads();

    for (int ep=0; ep<16; ++ep){
      if (ep < 15){
        float* Eh = E_lds + (c*2 + ((ep+1)&1))*1024;
        #pragma unroll
        for (int s=0;s<16;s++){
          float x2 = (leA[s] + peA[s].x*myt.x + peA[s].y*myt.y
                             + peA[s].z*myt.z + peA[s].w*myt.w)*LOG2E - PSC;
          Eh[s*64 + lane] = __builtin_amdgcn_exp2f(x2);
        }
        if (ep < 14){
          #pragma unroll
          for (int s=0;s<16;s++){
            int t = 256*c + 16*(ep+2) + s;
            leA[s] = leb[(size_t)t*32 + myl];
            peA[s] = *(const f32x4*)(peb + (size_t)t*4);
          }
        }
      }
      __syncthreads();
    }
  }
  __syncthreads();   // P_lds + L2arr + scpart visible

  // ================= PHASE 2: combine (wave 0) =================
  if (wv == 0){
    // start-mask sniff
    bool all01 = true, allf = true;
    #pragma unroll
    for (int k=0;k<16;k++){
      unsigned v = smask[k];
      all01 = all01 && (v <= 1u);
      allf  = allf  && (v == 0u || v == 0x3F800000u);
    }
    int startv;
    if (all01)      startv = ((const int*)smask)[lane];
    else if (allf)  startv = (((const unsigned*)smask)[lane] != 0u) ? 1 : 0;
    else            startv = ((const unsigned char*)smask)[lane];

    const int myl0 = t2l_lds[lane];
    const f32x4 myt0 = *(const f32x4*)(tp_lds + lane*4);
    f32x4 pe0 = *(const f32x4*)peb;
    float x0 = leb[myl0] + pe0.x*myt0.x + pe0.y*myt0.y + pe0.z*myt0.z + pe0.w*myt0.w;
    float v = startv ? __builtin_amdgcn_exp2f(x0*LOG2E - PSC) : 0.f;
    float L2p = 0.f;

    #pragma unroll 1
    for (int cc=0; cc<4; ++cc){
      pf[lane] = v;
      __builtin_amdgcn_wave_barrier();
      asm volatile("" ::: "memory");
      const float* Pr = P_lds + cc*4352 + lane*68;   // row `lane`
      float q = 0.f;
      #pragma unroll
      for (int k=0;k<16;k++){
        f32x4 vv = *(const f32x4*)(pf + 4*k);
        f32x4 pp = *(const f32x4*)(Pr + 4*k);
        q = fmaf(vv.x, pp.x, q); q = fmaf(vv.y, pp.y, q);
        q = fmaf(vv.z, pp.z, q); q = fmaf(vv.w, pp.w, q);
      }
      __builtin_amdgcn_wave_barrier();
      asm volatile("" ::: "memory");
      float S = wave_sum64(q);
      L2p += __builtin_amdgcn_logf(S);      // v_log_f32 = log2
      v = q * __builtin_amdgcn_rcpf(S);
    }
    if (lane == 0){
      float sct = (scpart[0]+scpart[1])+(scpart[2]+scpart[3])
                + (scpart[4]+scpart[5])+(scpart[6]+scpart[7]);
      float l2t = (L2arr[0]+L2arr[1])+(L2arr[2]+L2arr[3]);
      float logZ = LN2 * (l2t + L2p + PSC*1024.0f);
      out[b] = sct - logZ;
    }
  }
}

extern "C" void kernel_launch(void* const* d_in, const int* in_sizes, int n_in,
                              void* d_out, int out_size, void* d_ws, size_t ws_size,
                              hipStream_t stream)
{
  patcrf_fwd<<<256, 512, 0, stream>>>(
    (const float*)d_in[0],          // label_emissions [B,S,32]
    (const float*)d_in[1],          // pattern_emissions [B,S,4]
    (const int*)d_in[2],            // y [B,S]
    (const float*)d_in[3],          // label_transitions [32,32]
    (const int*)d_in[4],            // tag2label [64]
    (const float*)d_in[5],          // tag_patterns [64,4]
    (const float*)d_in[6],          // transition_constraints [64,64]
    (const unsigned int*)d_in[7],   // start_mask [64] (repr sniffed)
    (float*)d_out);
}

// Round 11
// 119.333 us; speedup vs baseline: 2.8147x; 1.0049x over previous
//
#include <hip/hip_runtime.h>

#define LOG2E 1.4426950408889634f
#define LN2   0.6931471805599453f
#define PSC   8.0f

typedef __attribute__((ext_vector_type(8))) short bf16x8;
typedef __attribute__((ext_vector_type(4))) float f32x4;
typedef __attribute__((ext_vector_type(4))) unsigned u32x4;

__device__ __forceinline__ unsigned pk_bf16(float lo, float hi){
  unsigned r;
  asm("v_cvt_pk_bf16_f32 %0, %1, %2" : "=v"(r) : "v"(lo), "v"(hi));
  return r;
}
// RNE f32->bf16 bit-ops (round-4-verified formula; position-unambiguous)
__device__ __forceinline__ unsigned short bf16_rne(float x){
  unsigned u = __float_as_uint(x);
  return (unsigned short)((u + 0x7FFFu + ((u>>16)&1u)) >> 16);
}

__device__ __forceinline__ float wave_sum64(float v){
#define DADD(ctrl) { int _t = __builtin_amdgcn_update_dpp(0, __float_as_int(v), ctrl, 0xF, 0xF, false); \
                     v = v + __int_as_float(_t); }
  DADD(0x111) DADD(0x112) DADD(0x114) DADD(0x118) DADD(0x142) DADD(0x143)
#undef DADD
  return __int_as_float(__builtin_amdgcn_readlane(__float_as_int(v), 63));
}
__device__ __forceinline__ float wave_max64(float v){
#define DMAX(ctrl) { int _t = __builtin_amdgcn_update_dpp(__float_as_int(v), __float_as_int(v), ctrl, 0xF, 0xF, false); \
                     v = fmaxf(v, __int_as_float(_t)); }
  DMAX(0x111) DMAX(0x112) DMAX(0x114) DMAX(0x118) DMAX(0x142) DMAX(0x143)
#undef DMAX
  return __int_as_float(__builtin_amdgcn_readlane(__float_as_int(v), 63));
}
__device__ __forceinline__ f32x4 vmax4(f32x4 a, f32x4 b){
  f32x4 r; r.x=fmaxf(a.x,b.x); r.y=fmaxf(a.y,b.y); r.z=fmaxf(a.z,b.z); r.w=fmaxf(a.w,b.w); return r;
}

// Block = batch. Waves 0-3: consumers; wave c runs TWO interleaved 128-step
// chains (A: t in [256c,256c+128), B: [256c+128,256c+256)), each P = prod
// D(e)W^T via 4x4 MFMA accumulators (r7-verified datapath). Waves 4-7:
// producers fill E[4][2buf][2half][16][64], double-buffered, __syncthreads
// per epoch (r7-verified). 8 epochs x 16 steps per chain.
// Epilogue: P bf16 to LDS; combine = 8 matvecs in wave 0.
__global__ void __launch_bounds__(512, 1)
patcrf_fwd(const float* __restrict__ le, const float* __restrict__ pe,
           const int* __restrict__ y, const float* __restrict__ lt,
           const int* __restrict__ t2l, const float* __restrict__ tp,
           const float* __restrict__ tc, const unsigned int* __restrict__ smask,
           float* __restrict__ out)
{
  const int b = blockIdx.x;
  const int tid = threadIdx.x;
  const int wv = tid >> 6;
  const int lane = tid & 63;
  const int bb = lane & 15, jj = lane >> 4;

  // phase1: trans[0,16K) | y[16K,20K) | E[20K,84K).  phase2: P bf16 [8][64][68] (69.6K)
  __shared__ __align__(16) char smem[86016];
  float* trans_lds = (float*)smem;
  int*   y_lds     = (int*)(smem + 16384);
  float* E_lds     = (float*)(smem + 20480);
  unsigned short* P_lds = (unsigned short*)smem;
  __shared__ __align__(16) float tp_lds[256];
  __shared__ __align__(16) float pf[64];
  __shared__ int   t2l_lds[64];
  __shared__ float scpart[8];
  __shared__ float L2arr[8];

  // ---- stage tables ----
  if (tid < 64){
    t2l_lds[tid] = t2l[tid];
    *(f32x4*)(tp_lds + tid*4) = *(const f32x4*)(tp + tid*4);
  }
  const int* yb = y + b*1024;
  y_lds[tid] = yb[tid];
  y_lds[tid+512] = yb[tid+512];
  __syncthreads();
  #pragma unroll
  for (int k=0;k<8;k++){
    int idx = k*512 + tid;
    trans_lds[idx] = lt[t2l_lds[idx>>6]*32 + t2l_lds[idx&63]] + tc[idx];
  }
  __syncthreads();

  const float* leb = le + (size_t)b*1024*32;
  const float* peb = pe + (size_t)b*1024*4;
  const int   myl  = t2l_lds[lane];
  const f32x4 mytp = *(const f32x4*)(tp_lds + lane*4);

  // ---- score phase: 2 positions per thread ----
  {
    int s0 = tid*2;
    int y0 = y_lds[s0], y1 = y_lds[s0+1];
    f32x4 pA = *(const f32x4*)(peb + (size_t)s0*4);
    f32x4 pB = *(const f32x4*)(peb + (size_t)(s0+1)*4);
    f32x4 tA = *(const f32x4*)(tp_lds + y0*4);
    f32x4 tB = *(const f32x4*)(tp_lds + y1*4);
    float s = leb[(size_t)s0*32 + t2l_lds[y0]]
            + pA.x*tA.x + pA.y*tA.y + pA.z*tA.z + pA.w*tA.w
            + leb[(size_t)(s0+1)*32 + t2l_lds[y1]]
            + pB.x*tB.x + pB.y*tB.y + pB.z*tB.z + pB.w*tB.w;
    s += trans_lds[y0*64 + y1];
    if (s0+2 < 1024) s += trans_lds[y1*64 + y_lds[s0+2]];
    float sw = wave_sum64(s);
    if (lane==0) scpart[wv] = sw;
  }

#define CSTEP(ACC, EPTR) do { \
    f32x4 ev[4]; \
    _Pragma("unroll") \
    for (int m_=0;m_<4;m_++) ev[m_] = *(const f32x4*)((EPTR) + 16*m_ + 4*jj); \
    u32x4 Bf[2][4]; \
    _Pragma("unroll") \
    for (int n_=0;n_<4;n_++){ \
      _Pragma("unroll") \
      for (int h_=0;h_<2;h_++){ \
        Bf[h_][n_] = (u32x4){ \
          pk_bf16(ACC[2*h_][n_].x,   ACC[2*h_][n_].y), \
          pk_bf16(ACC[2*h_][n_].z,   ACC[2*h_][n_].w), \
          pk_bf16(ACC[2*h_+1][n_].x, ACC[2*h_+1][n_].y), \
          pk_bf16(ACC[2*h_+1][n_].z, ACC[2*h_+1][n_].w) }; \
      } \
    } \
    _Pragma("unroll") \
    for (int m_=0;m_<4;m_++){ \
      _Pragma("unroll") \
      for (int n_=0;n_<4;n_++){ \
        f32x4 d_ = __builtin_amdgcn_mfma_f32_16x16x32_bf16( \
                     __builtin_bit_cast(bf16x8, Af[m_][0]), \
                     __builtin_bit_cast(bf16x8, Bf[0][n_]), zf, 0,0,0); \
        d_ = __builtin_amdgcn_mfma_f32_16x16x32_bf16( \
                     __builtin_bit_cast(bf16x8, Af[m_][1]), \
                     __builtin_bit_cast(bf16x8, Bf[1][n_]), d_, 0,0,0); \
        ACC[m_][n_] = d_ * ev[m_]; \
      } \
    } \
  } while(0)

#define RENORM(ACC, L2V) do { \
    f32x4 m4_ = ACC[0][0]; \
    _Pragma("unroll") \
    for (int m_=0;m_<4;m_++){ \
      _Pragma("unroll") \
      for (int n_=0;n_<4;n_++) m4_ = vmax4(m4_, ACC[m_][n_]); \
    } \
    float mx_ = fmaxf(fmaxf(m4_.x,m4_.y), fmaxf(m4_.z,m4_.w)); \
    mx_ = wave_max64(mx_); \
    if (mx_ > 0.f){ \
      int Ex_ = (int)(__float_as_uint(mx_)>>23) - 127; \
      if (Ex_ != 0){ \
        float scl_ = __uint_as_float((unsigned)(127 - Ex_) << 23); \
        _Pragma("unroll") \
        for (int m_=0;m_<4;m_++){ \
          _Pragma("unroll") \
          for (int n_=0;n_<4;n_++) ACC[m_][n_] = ACC[m_][n_]*scl_; \
        } \
        (L2V) += (float)Ex_; \
      } \
    } \
  } while(0)

  if (wv < 4){
    // ================= CONSUMER: two interleaved 128-step chains =============
    const int c = wv;
    u32x4 Af[4][2];
    #pragma unroll
    for (int m=0;m<4;m++){
      #pragma unroll
      for (int h=0;h<2;h++){
        unsigned uu[4];
        #pragma unroll
        for (int q=0;q<4;q++){
          int c0 = 2*q, c1 = 2*q+1;
          int sg0 = 32*h + ((c0>>2)<<4) + 4*jj + (c0&3);
          int sg1 = 32*h + ((c1>>2)<<4) + 4*jj + (c1&3);
          float w0 = __builtin_amdgcn_exp2f(trans_lds[sg0*64 + 16*m + bb]*LOG2E);
          float w1 = __builtin_amdgcn_exp2f(trans_lds[sg1*64 + 16*m + bb]*LOG2E);
          uu[q] = pk_bf16(w0, w1);
        }
        Af[m][h] = (u32x4){uu[0],uu[1],uu[2],uu[3]};
      }
    }
    f32x4 accA[4][4], accB[4][4];
    #pragma unroll
    for (int m=0;m<4;m++){
      #pragma unroll
      for (int n=0;n<4;n++){
        f32x4 z;
        z.x = (m==n && bb==4*jj+0) ? 1.f : 0.f;
        z.y = (m==n && bb==4*jj+1) ? 1.f : 0.f;
        z.z = (m==n && bb==4*jj+2) ? 1.f : 0.f;
        z.w = (m==n && bb==4*jj+3) ? 1.f : 0.f;
        accA[m][n] = z; accB[m][n] = z;
      }
    }
    float L2A = 0.f, L2B = 0.f;
    const f32x4 zf = {0.f,0.f,0.f,0.f};

    __syncthreads();   // E buf0 ready

    for (int ep=0; ep<8; ++ep){
      const float* EbA = E_lds + (c*4 + (ep&1)*2 + 0)*1024;
      const float* EbB = E_lds + (c*4 + (ep&1)*2 + 1)*1024;
      #pragma unroll 2
      for (int s=0;s<16;s++){
        if (!(c==0 && ep==0 && s==0)) CSTEP(accA, EbA + s*64);
        CSTEP(accB, EbB + s*64);
      }
      RENORM(accA, L2A);
      RENORM(accB, L2B);
      __syncthreads();
    }

    // P store: chain A -> chunk 2c, chain B -> chunk 2c+1 (phase-1 LDS dead)
    {
      unsigned short* PcA = P_lds + (2*c  )*4352;
      unsigned short* PcB = P_lds + (2*c+1)*4352;
      #pragma unroll
      for (int m=0;m<4;m++){
        #pragma unroll
        for (int n=0;n<4;n++){
          PcA[(16*m+4*jj+0)*68 + 16*n + bb] = bf16_rne(accA[m][n].x);
          PcA[(16*m+4*jj+1)*68 + 16*n + bb] = bf16_rne(accA[m][n].y);
          PcA[(16*m+4*jj+2)*68 + 16*n + bb] = bf16_rne(accA[m][n].z);
          PcA[(16*m+4*jj+3)*68 + 16*n + bb] = bf16_rne(accA[m][n].w);
          PcB[(16*m+4*jj+0)*68 + 16*n + bb] = bf16_rne(accB[m][n].x);
          PcB[(16*m+4*jj+1)*68 + 16*n + bb] = bf16_rne(accB[m][n].y);
          PcB[(16*m+4*jj+2)*68 + 16*n + bb] = bf16_rne(accB[m][n].z);
          PcB[(16*m+4*jj+3)*68 + 16*n + bb] = bf16_rne(accB[m][n].w);
        }
      }
      if (lane==0){ L2arr[2*c] = L2A; L2arr[2*c+1] = L2B; }
    }
  } else {
    // ================= PRODUCER: e(t) double-buffered epochs =================
    // wave 4+c serves consumer c: E[half h][step s] = e(256c + 128h + 16ep + s)
    const int c = wv - 4;
    const int base = 256*c;
    float leA[32]; f32x4 peA[32];
    // epoch 0 direct (buf 0): t = base + 128h + s, s<16
    #pragma unroll
    for (int k=0;k<32;k++){
      int t = base + 128*(k>>4) + (k&15);
      float l0 = leb[(size_t)t*32 + myl];
      f32x4 p0 = *(const f32x4*)(peb + (size_t)t*4);
      float x2 = (l0 + p0.x*mytp.x + p0.y*mytp.y + p0.z*mytp.z + p0.w*mytp.w)*LOG2E - PSC;
      E_lds[(c*4 + (k>>4))*1024 + (k&15)*64 + lane] = __builtin_amdgcn_exp2f(x2);
    }
    // raw epoch 1: t = base + 128h + 16 + s
    #pragma unroll
    for (int k=0;k<32;k++){
      int t = base + 128*(k>>4) + 16 + (k&15);
      leA[k] = leb[(size_t)t*32 + myl];
      peA[k] = *(const f32x4*)(peb + (size_t)t*4);
    }
    __syncthreads();   // E buf0 ready

    for (int ep=0; ep<8; ++ep){
      if (ep < 7){
        int buf = (ep+1)&1;
        #pragma unroll
        for (int k=0;k<32;k++){
          float x2 = (leA[k] + peA[k].x*mytp.x + peA[k].y*mytp.y
                             + peA[k].z*mytp.z + peA[k].w*mytp.w)*LOG2E - PSC;
          E_lds[(c*4 + buf*2 + (k>>4))*1024 + (k&15)*64 + lane] = __builtin_amdgcn_exp2f(x2);
        }
        if (ep < 6){
          // raw epoch ep+2: t = base + 128h + 16*(ep+2) + s  (max base+255)
          #pragma unroll
          for (int k=0;k<32;k++){
            int t = base + 128*(k>>4) + 16*(ep+2) + (k&15);
            leA[k] = leb[(size_t)t*32 + myl];
            peA[k] = *(const f32x4*)(peb + (size_t)t*4);
          }
        }
      }
      __syncthreads();
    }
  }

  __syncthreads();   // P + L2arr + scpart visible to all

  // ================= combine (wave 0) =================
  if (wv == 0){
    bool all01 = true, allf = true;
    #pragma unroll
    for (int k=0;k<16;k++){
      unsigned v = smask[k];
      all01 = all01 && (v <= 1u);
      allf  = allf  && (v == 0u || v == 0x3F800000u);
    }
    int startv;
    if (all01)      startv = ((const int*)smask)[lane];
    else if (allf)  startv = (((const unsigned*)smask)[lane] != 0u) ? 1 : 0;
    else            startv = ((const unsigned char*)smask)[lane];

    f32x4 pe0 = *(const f32x4*)peb;
    float x0 = leb[myl] + pe0.x*mytp.x + pe0.y*mytp.y + pe0.z*mytp.z + pe0.w*mytp.w;
    float v = startv ? __builtin_amdgcn_exp2f(x0*LOG2E - PSC) : 0.f;
    float L2p = 0.f;

    #pragma unroll 1
    for (int cc=0; cc<8; ++cc){
      pf[lane] = v;
      __builtin_amdgcn_wave_barrier();
      asm volatile("" ::: "memory");
      const unsigned short* Pr = P_lds + cc*4352 + lane*68;   // own row
      float q = 0.f;
      #pragma unroll
      for (int k=0;k<16;k++){
        uint2 u = *(const uint2*)(Pr + 4*k);
        f32x4 vv = *(const f32x4*)(pf + 4*k);
        q = fmaf(__uint_as_float(u.x << 16),          vv.x, q);
        q = fmaf(__uint_as_float(u.x & 0xFFFF0000u),  vv.y, q);
        q = fmaf(__uint_as_float(u.y << 16),          vv.z, q);
        q = fmaf(__uint_as_float(u.y & 0xFFFF0000u),  vv.w, q);
      }
      __builtin_amdgcn_wave_barrier();
      asm volatile("" ::: "memory");
      float S = wave_sum64(q);
      L2p += __builtin_amdgcn_logf(S);      // v_log_f32 = log2
      v = q * __builtin_amdgcn_rcpf(S);
    }
    if (lane == 0){
      float sct = ((scpart[0]+scpart[1])+(scpart[2]+scpart[3]))
                + ((scpart[4]+scpart[5])+(scpart[6]+scpart[7]));
      float l2t = ((L2arr[0]+L2arr[1])+(L2arr[2]+L2arr[3]))
                + ((L2arr[4]+L2arr[5])+(L2arr[6]+L2arr[7]));
      float logZ = LN2 * (l2t + L2p + PSC*1024.0f);
      out[b] = sct - logZ;
    }
  }
#undef CSTEP
#undef RENORM
}

extern "C" void kernel_launch(void* const* d_in, const int* in_sizes, int n_in,
                              void* d_out, int out_size, void* d_ws, size_t ws_size,
                              hipStream_t stream)
{
  patcrf_fwd<<<256, 512, 0, stream>>>(
    (const float*)d_in[0],          // label_emissions [B,S,32]
    (const float*)d_in[1],          // pattern_emissions [B,S,4]
    (const int*)d_in[2],            // y [B,S]
    (const float*)d_in[3],          // label_transitions [32,32]
    (const int*)d_in[4],            // tag2label [64]
    (const float*)d_in[5],          // tag_patterns [64,4]
    (const float*)d_in[6],          // transition_constraints [64,64]
    (const unsigned int*)d_in[7],   // start_mask [64] (repr sniffed)
    (float*)d_out);
}